// Round 6
// baseline (386.262 us; speedup 1.0000x reference)
//
#include <hip/hip_runtime.h>

// VectorQuantizer on MI355X — R6: barrier-free K-loop.
// R5 post-mortem: all global_load_lds + vmcnt(0)+s_barrier per-tile structures plateau
// at ~300us (m97-plateau mechanism). R6 removes LDS staging for B entirely: femb is
// packed in fragment order, so each lane global_load_dwordx4's its own B-fragment into
// VGPRs. Waves partition CODES; each wave holds all 64 A-rows in registers. Zero
// barriers in the K-loop -> compiler software-pipelines loads (AITER-style vmcnt(N)).

#define D        256
#define KCODES   8192
#define NROWS    32768
#define MB       64       // rows per block
#define CHUNKS   512      // 8192 codes / 16 per chunk
#define THREADS  256
#define CAP      32
#define MARGIN   0.03f    // f16 score err bound ~7e-3; margin covers approx-vs-exact
#define BIAS     32.0f    // scores shifted positive so int-compare == float-compare
#define NOUT     8388608

typedef _Float16 h8_t __attribute__((ext_vector_type(8)));
typedef float    f4_t __attribute__((ext_vector_type(4)));

__device__ __forceinline__ float clipf(float v) { return fminf(1.0f, fmaxf(-1.0f, v)); }

#define DPP_ROR(x, n) __int_as_float(__builtin_amdgcn_update_dpp( \
    0, __float_as_int(x), 0x120 + (n), 0xF, 0xF, true))
__device__ __forceinline__ float maxrow16(float x) {
  x = fmaxf(x, DPP_ROR(x, 1));
  x = fmaxf(x, DPP_ROR(x, 2));
  x = fmaxf(x, DPP_ROR(x, 4));
  x = fmaxf(x, DPP_ROR(x, 8));
  return x;
}

// ---- pack f16 codebook, chunk-major fragment order + numpy-order sum(e^2) ----
// chunk ch (16 codes) = 8KB: 16B unit u in [0,512): kc=u>>6, ln=u&63;
// content = emb16[ch*16 + (ln&15)][kc*32 + (ln>>4)*8 .. +8]
__global__ void vq_packsetup(const float* __restrict__ emb, _Float16* __restrict__ femb,
                             float* __restrict__ senp, float* __restrict__ ekkb,
                             float* __restrict__ lossacc) {
  const int t = blockIdx.x;   // 256 blocks; block covers 2 chunks = 32 codes
  if (t == 0 && threadIdx.x == 0) lossacc[0] = 0.0f;
  #pragma unroll
  for (int j = 0; j < 4; ++j) {
    int g = t * 1024 + j * 256 + threadIdx.x;   // global 16B unit
    int ch = g >> 9, u = g & 511;
    int kc = u >> 6, ln = u & 63;
    int code = ch * 16 + (ln & 15);
    int k0 = kc * 32 + (ln >> 4) * 8;
    const float* sp = emb + (size_t)code * D + k0;
    f4_t v0 = *(const f4_t*)sp, v1 = *(const f4_t*)(sp + 4);
    h8_t h;
    h[0] = (_Float16)v0[0]; h[1] = (_Float16)v0[1];
    h[2] = (_Float16)v0[2]; h[3] = (_Float16)v0[3];
    h[4] = (_Float16)v1[0]; h[5] = (_Float16)v1[1];
    h[6] = (_Float16)v1[2]; h[7] = (_Float16)v1[3];
    *(h8_t*)(femb + (size_t)g * 8) = h;
  }
  // numpy-pairwise-order sum(e^2); butterfly == same binary tree (commutative reorder only)
  const int lane = threadIdx.x & 63;
  const int w    = threadIdx.x >> 6;
  const int jdx  = lane & 15, hf = jdx >> 3, jj = jdx & 7;
  #pragma unroll
  for (int cc = 0; cc < 2; ++cc) {
    int k = t * 32 + w * 8 + cc * 4 + (lane >> 4);
    const float* base = emb + (size_t)k * D + hf * 128 + jj;
    float v = base[0];
    float r = v * v;
    #pragma unroll
    for (int m = 1; m < 16; ++m) { v = base[8 * m]; r += v * v; }
    r += __shfl_xor(r, 1, 64);
    r += __shfl_xor(r, 2, 64);
    r += __shfl_xor(r, 4, 64);
    r += __shfl_xor(r, 8, 64);
    if (jdx == 0) { senp[k] = r; ekkb[k] = 0.5f * r - BIAS; }
  }
}

// ---------------- main ----------------
__global__ void __launch_bounds__(THREADS, 2)
vq_main(const float* __restrict__ xin, const _Float16* __restrict__ femb,
        const float* __restrict__ emb, const float* __restrict__ senp,
        const float* __restrict__ ekkb, float* __restrict__ out,
        float* __restrict__ lossacc) {
  __shared__ alignas(16) char Astage[32768];   // A staging; reused as rescore scratch
  __shared__ float Eks[KCODES];                // 32 KB
  __shared__ int rowmaxI[MB];
  __shared__ int cnt[MB];
  __shared__ unsigned short cand[MB][CAP];     // 4 KB
  __shared__ float blksum;                     // ~69 KB total -> 2 blocks/CU

  const int tid  = threadIdx.x;
  const int lane = tid & 63;
  const int wid  = tid >> 6;     // 0..3 : code partition
  const int l15  = lane & 15;
  const int quad = lane >> 4;
  const int r0   = blockIdx.x * MB;

  for (int i = tid; i < MB; i += THREADS) { rowmaxI[i] = 0; cnt[i] = 0; }
  if (tid == 0) blksum = 0.0f;

  // ---- Eks into LDS (lgkm-only in K-loop)
  #pragma unroll
  for (int i = 0; i < 8; ++i) {
    int e = (i * THREADS + tid) * 4;
    *(f4_t*)&Eks[e] = *(const f4_t*)&ekkb[e];
  }

  // ---- stage A (clip + f16, chunk-major fragment order: 64 rows x 256 k = 2048 units)
  #pragma unroll
  for (int j = 0; j < 8; ++j) {
    int c = j * THREADS + tid;          // 0..2047
    int ms = c >> 9, kc = (c >> 6) & 7, ln = c & 63;
    int row = ms * 16 + (ln & 15);
    int k0 = kc * 32 + (ln >> 4) * 8;
    const float* ap = xin + (size_t)(r0 + row) * D + k0;
    f4_t v0 = *(const f4_t*)ap, v1 = *(const f4_t*)(ap + 4);
    h8_t h;
    h[0] = (_Float16)clipf(v0[0]); h[1] = (_Float16)clipf(v0[1]);
    h[2] = (_Float16)clipf(v0[2]); h[3] = (_Float16)clipf(v0[3]);
    h[4] = (_Float16)clipf(v1[0]); h[5] = (_Float16)clipf(v1[1]);
    h[6] = (_Float16)clipf(v1[2]); h[7] = (_Float16)clipf(v1[3]);
    *(h8_t*)(Astage + (size_t)c * 16) = h;
  }
  __syncthreads();

  // ---- A fragments -> registers: all 64 rows per wave (128 VGPR)
  h8_t afrag[4][8];
  #pragma unroll
  for (int ms = 0; ms < 4; ++ms)
    #pragma unroll
    for (int kc = 0; kc < 8; ++kc)
      afrag[ms][kc] = *(const h8_t*)(Astage + (size_t)((ms * 512 + kc * 64 + lane) * 16));

  // ---- barrier-free K-loop: each wave streams its quarter of the 512 chunks
  float Gm[4];
  #pragma unroll
  for (int a = 0; a < 4; ++a) Gm[a] = -1e30f;

  for (int ch = wid; ch < CHUNKS; ch += 4) {
    const _Float16* bb = femb + (size_t)ch * 4096 + lane * 8;
    h8_t b[8];
    #pragma unroll
    for (int kc = 0; kc < 8; ++kc) b[kc] = *(const h8_t*)(bb + kc * 512);
    float ekk = Eks[ch * 16 + l15];
    f4_t acc[4];
    #pragma unroll
    for (int ms = 0; ms < 4; ++ms) { f4_t z = {0.f, 0.f, 0.f, 0.f}; acc[ms] = z; }
    #pragma unroll
    for (int kc = 0; kc < 8; ++kc)
      #pragma unroll
      for (int ms = 0; ms < 4; ++ms)
        acc[ms] = __builtin_amdgcn_mfma_f32_16x16x32_f16(afrag[ms][kc], b[kc], acc[ms], 0, 0, 0);

    #pragma unroll
    for (int ms = 0; ms < 4; ++ms) {
      float ts[4];
      #pragma unroll
      for (int r = 0; r < 4; ++r) ts[r] = acc[ms][r] - ekk;
      float tmx = fmaxf(fmaxf(ts[0], ts[1]), fmaxf(ts[2], ts[3]));
      if (__any(tmx > Gm[ms])) {       // register gate: Gm = min of the 4 row-cuts seen
        float cmin = 1e30f;
        #pragma unroll
        for (int r = 0; r < 4; ++r) {
          int row_ = ms * 16 + quad * 4 + r;
          float mm = maxrow16(ts[r]);
          if (l15 == 0) atomicMax(&rowmaxI[row_], __float_as_int(mm));
          float cut = __int_as_float(rowmaxI[row_]) - MARGIN;
          cmin = fminf(cmin, cut);
          if (ts[r] >= cut) {
            int s = atomicAdd(&cnt[row_], 1);
            if (s < CAP) cand[row_][s] = (unsigned short)(ch * 16 + l15);
          }
        }
        Gm[ms] = cmin;
      }
    }
  }
  __syncthreads();   // all waves' candidates visible

  // ---------------- exact rescore + output + loss (scratch over Astage) ----------------
  float* xrow  = (float*)Astage;           // 4 waves x 256 floats
  float* rpart = (float*)(Astage + 4096);  // 4 waves x 16 floats
  const int lane4 = lane * 4;
  for (int rr = 0; rr < 16; ++rr) {
    const int row = wid + rr * 4;
    f4_t xv = *(const f4_t*)(xin + (size_t)(r0 + row) * D + lane4);
    xv[0] = clipf(xv[0]); xv[1] = clipf(xv[1]); xv[2] = clipf(xv[2]); xv[3] = clipf(xv[3]);
    *(f4_t*)&xrow[wid * 256 + lane4] = xv;
    __builtin_amdgcn_wave_barrier();
    if (lane < 16) {   // numpy pairwise sum of x^2 (exact order)
      const int hf = lane >> 3, jj = lane & 7;
      const float* base = &xrow[wid * 256 + hf * 128 + jj];
      float v = base[0];
      float rs = v * v;
      #pragma unroll
      for (int m = 1; m < 16; ++m) { v = base[8 * m]; rs += v * v; }
      rpart[wid * 16 + lane] = rs;
    }
    __builtin_amdgcn_wave_barrier();
    float p[16];
    #pragma unroll
    for (int j = 0; j < 16; ++j) p[j] = rpart[wid * 16 + j];
    float h0 = ((p[0] + p[1]) + (p[2] + p[3])) + ((p[4] + p[5]) + (p[6] + p[7]));
    float h1 = ((p[8] + p[9]) + (p[10] + p[11])) + ((p[12] + p[13]) + (p[14] + p[15]));
    float sx = h0 + h1;

    int nc = cnt[row]; nc = nc > CAP ? CAP : nc;
    float bd = INFINITY; int bk = 0;
    for (int ci = 0; ci < nc; ++ci) {
      int k = cand[row][ci];
      f4_t ev = *(const f4_t*)(emb + (size_t)k * D + lane4);
      double dd = (double)xv[0] * (double)ev[0] + (double)xv[1] * (double)ev[1]
                + (double)xv[2] * (double)ev[2] + (double)xv[3] * (double)ev[3];
      #pragma unroll
      for (int off = 1; off < 64; off <<= 1) dd += __shfl_xor(dd, off, 64);
      float T1 = sx + senp[k];          // fp32, numpy op order
      float T2 = (float)(2.0 * dd);     // fp32-rounded 2*dot
      float d  = T1 - T2;               // final fp32 quantization like numpy
      if (d < bd || (d == bd && k < bk)) { bd = d; bk = k; }
    }

    f4_t ev = *(const f4_t*)(emb + (size_t)bk * D + lane4);
    *(f4_t*)(out + (size_t)(r0 + row) * D + lane4) = ev;
    float ls = 0.0f;
    #pragma unroll
    for (int i = 0; i < 4; ++i) { float df = ev[i] - xv[i]; ls += df * df; }
    #pragma unroll
    for (int off = 1; off < 64; off <<= 1) ls += __shfl_xor(ls, off, 64);
    if (lane == 0) atomicAdd(&blksum, ls);
  }
  __syncthreads();
  if (tid == 0) atomicAdd(lossacc, blksum);
}

// ---------------- finalize loss ----------------
__global__ void vq_fin(const float* __restrict__ lossacc, float* __restrict__ out) {
  out[NOUT] = 1.25f * lossacc[0] / 8388608.0f;
}

extern "C" void kernel_launch(void* const* d_in, const int* in_sizes, int n_in,
                              void* d_out, int out_size, void* d_ws, size_t ws_size,
                              hipStream_t stream) {
  const float* xin = (const float*)d_in[0];
  const float* emb = (const float*)d_in[1];
  float* out = (float*)d_out;
  _Float16* femb = (_Float16*)d_ws;                 // 4 MB (512 chunks x 8 KB)
  float* wsf     = (float*)d_ws;
  float* senp    = wsf + 1048576;                   // 8192 floats
  float* ekkb    = senp + KCODES;                   // 8192 floats
  float* lossacc = ekkb + KCODES;                   // 1 float
  vq_packsetup<<<dim3(256), dim3(256), 0, stream>>>(emb, femb, senp, ekkb, lossacc);
  vq_main<<<dim3(NROWS / MB), dim3(THREADS), 0, stream>>>(xin, femb, emb, senp, ekkb, out, lossacc);
  vq_fin<<<dim3(1), dim3(1), 0, stream>>>(lossacc, out);
}

// Round 7
// 382.908 us; speedup vs baseline: 1.0088x; 1.0088x over previous
//
#include <hip/hip_runtime.h>

// VectorQuantizer on MI355X — R7.
// R6 post-mortem: MFMA-busy is ~57us in EVERY structure; the plateau is Infinity-Cache
// BW: each block circularly streams the 4MB femb through a 4MB LRU L2 -> ~0% L2 hits
// (self-thrash) -> 512x4MB=2GB from L3 @ ~8TB/s ~ 250us. R7: (1) MB=128 halves total
// traffic; (2) codebook swept in 4 phases of 1MB, grid=256 (1 block/CU) in lockstep ->
// phase window is L2-resident; (3) rescore split into its own high-occupancy kernel.

#define D        256
#define KCODES   8192
#define NROWS    32768
#define MB       128      // rows per block
#define CHUNKS   512      // total 16-code chunks
#define PHASES   4        // 128 chunks (1 MB) per phase -> L2-resident window
#define THREADS  512
#define CAP      32
#define MARGIN   0.03f    // f16 score err bound ~7e-3
#define BIAS     32.0f    // scores shifted positive so int-compare == float-compare
#define NOUT     8388608

typedef _Float16 h8_t __attribute__((ext_vector_type(8)));
typedef float    f4_t __attribute__((ext_vector_type(4)));

__device__ __forceinline__ float clipf(float v) { return fminf(1.0f, fmaxf(-1.0f, v)); }

#define DPP_ROR(x, n) __int_as_float(__builtin_amdgcn_update_dpp( \
    0, __float_as_int(x), 0x120 + (n), 0xF, 0xF, true))
__device__ __forceinline__ float maxrow16(float x) {
  x = fmaxf(x, DPP_ROR(x, 1));
  x = fmaxf(x, DPP_ROR(x, 2));
  x = fmaxf(x, DPP_ROR(x, 4));
  x = fmaxf(x, DPP_ROR(x, 8));
  return x;
}

// ---- pack f16 codebook, chunk-major fragment order + numpy-order sum(e^2) ----
__global__ void vq_packsetup(const float* __restrict__ emb, _Float16* __restrict__ femb,
                             float* __restrict__ senp, float* __restrict__ ekkb,
                             float* __restrict__ lossacc) {
  const int t = blockIdx.x;   // 256 blocks, 32 codes each
  if (t == 0 && threadIdx.x == 0) lossacc[0] = 0.0f;
  #pragma unroll
  for (int j = 0; j < 4; ++j) {
    int g = t * 1024 + j * 256 + threadIdx.x;   // global 16B unit
    int ch = g >> 9, u = g & 511;
    int kc = u >> 6, ln = u & 63;
    int code = ch * 16 + (ln & 15);
    int k0 = kc * 32 + (ln >> 4) * 8;
    const float* sp = emb + (size_t)code * D + k0;
    f4_t v0 = *(const f4_t*)sp, v1 = *(const f4_t*)(sp + 4);
    h8_t h;
    h[0] = (_Float16)v0[0]; h[1] = (_Float16)v0[1];
    h[2] = (_Float16)v0[2]; h[3] = (_Float16)v0[3];
    h[4] = (_Float16)v1[0]; h[5] = (_Float16)v1[1];
    h[6] = (_Float16)v1[2]; h[7] = (_Float16)v1[3];
    *(h8_t*)(femb + (size_t)g * 8) = h;
  }
  const int lane = threadIdx.x & 63;
  const int w    = threadIdx.x >> 6;
  const int jdx  = lane & 15, hf = jdx >> 3, jj = jdx & 7;
  #pragma unroll
  for (int cc = 0; cc < 2; ++cc) {
    int k = t * 32 + w * 8 + cc * 4 + (lane >> 4);
    const float* base = emb + (size_t)k * D + hf * 128 + jj;
    float v = base[0];
    float r = v * v;
    #pragma unroll
    for (int m = 1; m < 16; ++m) { v = base[8 * m]; r += v * v; }
    r += __shfl_xor(r, 1, 64);
    r += __shfl_xor(r, 2, 64);
    r += __shfl_xor(r, 4, 64);
    r += __shfl_xor(r, 8, 64);
    if (jdx == 0) { senp[k] = r; ekkb[k] = 0.5f * r - BIAS; }
  }
}

// ---------------- score: MFMA + margin filter -> global candidate lists ----------------
__global__ void __launch_bounds__(THREADS, 2)
vq_score(const float* __restrict__ xin, const _Float16* __restrict__ femb,
         const float* __restrict__ ekkb, int* __restrict__ gcnt,
         unsigned short* __restrict__ gcand) {
  __shared__ alignas(16) char Astage[65536];   // 128 rows x 256 k f16, fragment order
  __shared__ float Eks[KCODES];                // 32 KB
  __shared__ int rowmaxI[MB];
  __shared__ int cnt[MB];
  __shared__ unsigned short cand[MB][CAP];     // 8 KB;  total ~107 KB -> 1 block/CU

  const int tid  = threadIdx.x;
  const int lane = tid & 63;
  const int wid  = tid >> 6;     // 0..7
  const int l15  = lane & 15;
  const int quad = lane >> 4;
  const int rw   = wid >> 2;     // 0..1 : 64-row half
  const int cq   = wid & 3;      // 0..3 : code quarter
  const int r0   = blockIdx.x * MB;

  for (int i = tid; i < MB; i += THREADS) { rowmaxI[i] = 0; cnt[i] = 0; }

  // Eks into LDS
  #pragma unroll
  for (int i = 0; i < 4; ++i) {
    int e = (i * THREADS + tid) * 4;
    *(f4_t*)&Eks[e] = *(const f4_t*)&ekkb[e];
  }

  // stage A (clip + f16, chunk-major fragment order: 128 rows x 256 k = 4096 units)
  #pragma unroll
  for (int j = 0; j < 8; ++j) {
    int c = j * THREADS + tid;          // 0..4095
    int ms = c >> 9, kc = (c >> 6) & 7, ln = c & 63;
    int row = ms * 16 + (ln & 15);
    int k0 = kc * 32 + (ln >> 4) * 8;
    const float* ap = xin + (size_t)(r0 + row) * D + k0;
    f4_t v0 = *(const f4_t*)ap, v1 = *(const f4_t*)(ap + 4);
    h8_t h;
    h[0] = (_Float16)clipf(v0[0]); h[1] = (_Float16)clipf(v0[1]);
    h[2] = (_Float16)clipf(v0[2]); h[3] = (_Float16)clipf(v0[3]);
    h[4] = (_Float16)clipf(v1[0]); h[5] = (_Float16)clipf(v1[1]);
    h[6] = (_Float16)clipf(v1[2]); h[7] = (_Float16)clipf(v1[3]);
    *(h8_t*)(Astage + (size_t)c * 16) = h;
  }
  __syncthreads();

  // A fragments -> registers: 64 rows per wave (rw half), 128 VGPR
  h8_t afrag[4][8];
  #pragma unroll
  for (int m = 0; m < 4; ++m)
    #pragma unroll
    for (int kc = 0; kc < 8; ++kc)
      afrag[m][kc] = *(const h8_t*)(Astage +
          (size_t)(((rw * 4 + m) * 512 + kc * 64 + lane) * 16));

  float Gm[4];
  #pragma unroll
  for (int a = 0; a < 4; ++a) Gm[a] = -1e30f;

  // K-loop in 4 lockstep phases of 1 MB (L2-resident window); no per-chunk barriers
  for (int p = 0; p < PHASES; ++p) {
    for (int j = 0; j < CHUNKS / PHASES / 4; ++j) {
      const int ch = p * (CHUNKS / PHASES) + cq + j * 4;
      const _Float16* bb = femb + (size_t)ch * 4096 + lane * 8;
      h8_t b[8];
      #pragma unroll
      for (int kc = 0; kc < 8; ++kc) b[kc] = *(const h8_t*)(bb + kc * 512);
      float ekk = Eks[ch * 16 + l15];
      f4_t acc[4];
      #pragma unroll
      for (int m = 0; m < 4; ++m) { f4_t z = {0.f, 0.f, 0.f, 0.f}; acc[m] = z; }
      #pragma unroll
      for (int kc = 0; kc < 8; ++kc)
        #pragma unroll
        for (int m = 0; m < 4; ++m)
          acc[m] = __builtin_amdgcn_mfma_f32_16x16x32_f16(afrag[m][kc], b[kc], acc[m], 0, 0, 0);

      #pragma unroll
      for (int m = 0; m < 4; ++m) {
        float ts[4];
        #pragma unroll
        for (int r = 0; r < 4; ++r) ts[r] = acc[m][r] - ekk;
        float tmx = fmaxf(fmaxf(ts[0], ts[1]), fmaxf(ts[2], ts[3]));
        if (__any(tmx > Gm[m])) {
          float cmin = 1e30f;
          #pragma unroll
          for (int r = 0; r < 4; ++r) {
            int row_ = rw * 64 + m * 16 + quad * 4 + r;
            float mm = maxrow16(ts[r]);
            if (l15 == 0) atomicMax(&rowmaxI[row_], __float_as_int(mm));
            float cut = __int_as_float(rowmaxI[row_]) - MARGIN;
            cmin = fminf(cmin, cut);
            if (ts[r] >= cut) {
              int s = atomicAdd(&cnt[row_], 1);
              if (s < CAP) cand[row_][s] = (unsigned short)(ch * 16 + l15);
            }
          }
          Gm[m] = cmin;
        }
      }
    }
    __syncthreads();   // keep all 8 waves (and ~all blocks) in the same 1MB window
  }

  // dump candidates to global
  for (int i = tid; i < MB; i += THREADS) {
    int c = cnt[i];
    gcnt[r0 + i] = c > CAP ? CAP : c;
  }
  const unsigned int* cu = (const unsigned int*)cand;
  unsigned int* gu = (unsigned int*)gcand + (size_t)r0 * (CAP / 2);
  for (int i = tid; i < MB * (CAP / 2); i += THREADS) gu[i] = cu[i];
}

// ---------------- exact rescore + output + loss (high occupancy) ----------------
__global__ void __launch_bounds__(256)
vq_rescore(const float* __restrict__ xin, const float* __restrict__ emb,
           const float* __restrict__ senp, const int* __restrict__ gcnt,
           const unsigned short* __restrict__ gcand, float* __restrict__ out,
           float* __restrict__ lossacc) {
  __shared__ float xrow[4][D];
  __shared__ float rpart[4][16];
  __shared__ float blksum;
  const int tid  = threadIdx.x;
  const int lane = tid & 63;
  const int wid  = tid >> 6;
  const int r0   = blockIdx.x * 64;
  if (tid == 0) blksum = 0.0f;
  __syncthreads();

  const int lane4 = lane * 4;
  for (int rr = 0; rr < 16; ++rr) {
    const int row = wid + rr * 4;
    f4_t xv = *(const f4_t*)(xin + (size_t)(r0 + row) * D + lane4);
    xv[0] = clipf(xv[0]); xv[1] = clipf(xv[1]); xv[2] = clipf(xv[2]); xv[3] = clipf(xv[3]);
    *(f4_t*)&xrow[wid][lane4] = xv;
    __builtin_amdgcn_wave_barrier();
    if (lane < 16) {   // numpy pairwise sum of x^2 (exact order)
      const int hf = lane >> 3, jj = lane & 7;
      const float* base = &xrow[wid][hf * 128 + jj];
      float v = base[0];
      float rs = v * v;
      #pragma unroll
      for (int m = 1; m < 16; ++m) { v = base[8 * m]; rs += v * v; }
      rpart[wid][lane] = rs;
    }
    __builtin_amdgcn_wave_barrier();
    float p[16];
    #pragma unroll
    for (int j = 0; j < 16; ++j) p[j] = rpart[wid][j];
    float h0 = ((p[0] + p[1]) + (p[2] + p[3])) + ((p[4] + p[5]) + (p[6] + p[7]));
    float h1 = ((p[8] + p[9]) + (p[10] + p[11])) + ((p[12] + p[13]) + (p[14] + p[15]));
    float sx = h0 + h1;

    int nc = gcnt[r0 + row];
    const unsigned short* cl = gcand + (size_t)(r0 + row) * CAP;
    float bd = INFINITY; int bk = 0;
    for (int ci = 0; ci < nc; ++ci) {
      int k = cl[ci];
      f4_t ev = *(const f4_t*)(emb + (size_t)k * D + lane4);
      double dd = (double)xv[0] * (double)ev[0] + (double)xv[1] * (double)ev[1]
                + (double)xv[2] * (double)ev[2] + (double)xv[3] * (double)ev[3];
      #pragma unroll
      for (int off = 1; off < 64; off <<= 1) dd += __shfl_xor(dd, off, 64);
      float T1 = sx + senp[k];          // fp32, numpy op order
      float T2 = (float)(2.0 * dd);     // fp32-rounded 2*dot
      float d  = T1 - T2;               // final fp32 quantization like numpy
      if (d < bd || (d == bd && k < bk)) { bd = d; bk = k; }
    }

    f4_t ev = *(const f4_t*)(emb + (size_t)bk * D + lane4);
    *(f4_t*)(out + (size_t)(r0 + row) * D + lane4) = ev;
    float ls = 0.0f;
    #pragma unroll
    for (int i = 0; i < 4; ++i) { float df = ev[i] - xv[i]; ls += df * df; }
    #pragma unroll
    for (int off = 1; off < 64; off <<= 1) ls += __shfl_xor(ls, off, 64);
    if (lane == 0) atomicAdd(&blksum, ls);
  }
  __syncthreads();
  if (tid == 0) atomicAdd(lossacc, blksum);
}

// ---------------- finalize loss ----------------
__global__ void vq_fin(const float* __restrict__ lossacc, float* __restrict__ out) {
  out[NOUT] = 1.25f * lossacc[0] / 8388608.0f;
}

extern "C" void kernel_launch(void* const* d_in, const int* in_sizes, int n_in,
                              void* d_out, int out_size, void* d_ws, size_t ws_size,
                              hipStream_t stream) {
  const float* xin = (const float*)d_in[0];
  const float* emb = (const float*)d_in[1];
  float* out = (float*)d_out;
  _Float16* femb = (_Float16*)d_ws;                 // 4 MB (512 chunks x 8 KB)
  float* F       = (float*)d_ws + 1048576;
  float* senp    = F;                               // 8192
  float* ekkb    = F + 8192;                        // 8192
  float* lossacc = F + 16384;                       // 1
  int*   gcnt    = (int*)(F + 16640);               // 32768 ints (128 KB)
  unsigned short* gcand = (unsigned short*)(F + 16640 + 32768);  // 32768*32 u16 (2 MB)
  vq_packsetup<<<dim3(256), dim3(256), 0, stream>>>(emb, femb, senp, ekkb, lossacc);
  vq_score<<<dim3(NROWS / MB), dim3(THREADS), 0, stream>>>(xin, femb, ekkb, gcnt, gcand);
  vq_rescore<<<dim3(NROWS / 64), dim3(256), 0, stream>>>(xin, emb, senp, gcnt, gcand, out, lossacc);
  vq_fin<<<dim3(1), dim3(1), 0, stream>>>(lossacc, out);
}

// Round 8
// 313.914 us; speedup vs baseline: 1.2305x; 1.2198x over previous
//
#include <hip/hip_runtime.h>

// VectorQuantizer on MI355X — R8.
// R7 post-mortem: score = 33% of its own per-CU MFMA floor (66us); serial
// load->wait->MFMA chunks with 2 waves/SIMD and no reg pipelining. Rescore ~150us
// (serial 6-level double shuffle chains). R8: (1) score K-loop explicitly
// double-buffers B+ekk in REGISTERS (all waits vmcnt(9), never 0; Eks LDS dropped);
// (2) rescore: 8 lanes/candidate octant-dot + butterfly argmin (exact semantics).

#define D        256
#define KCODES   8192
#define NROWS    32768
#define MB       128      // rows per block (score)
#define SLOTS    128      // chunk-slots per wave (512 chunks / 4 code-quarters)
#define THREADS  512
#define CAP      32
#define MARGIN   0.03f    // f16 score err bound ~7e-3
#define BIAS     32.0f    // scores shifted positive so int-compare == float-compare
#define NOUT     8388608

typedef _Float16 h8_t __attribute__((ext_vector_type(8)));
typedef float    f4_t __attribute__((ext_vector_type(4)));

__device__ __forceinline__ float clipf(float v) { return fminf(1.0f, fmaxf(-1.0f, v)); }

#define DPP_ROR(x, n) __int_as_float(__builtin_amdgcn_update_dpp( \
    0, __float_as_int(x), 0x120 + (n), 0xF, 0xF, true))
__device__ __forceinline__ float maxrow16(float x) {
  x = fmaxf(x, DPP_ROR(x, 1));
  x = fmaxf(x, DPP_ROR(x, 2));
  x = fmaxf(x, DPP_ROR(x, 4));
  x = fmaxf(x, DPP_ROR(x, 8));
  return x;
}

// ---- pack f16 codebook, chunk-major fragment order + numpy-order sum(e^2) ----
__global__ void vq_packsetup(const float* __restrict__ emb, _Float16* __restrict__ femb,
                             float* __restrict__ senp, float* __restrict__ ekkb,
                             float* __restrict__ lossacc) {
  const int t = blockIdx.x;   // 256 blocks, 32 codes each
  if (t == 0 && threadIdx.x == 0) lossacc[0] = 0.0f;
  #pragma unroll
  for (int j = 0; j < 4; ++j) {
    int g = t * 1024 + j * 256 + threadIdx.x;   // global 16B unit
    int ch = g >> 9, u = g & 511;
    int kc = u >> 6, ln = u & 63;
    int code = ch * 16 + (ln & 15);
    int k0 = kc * 32 + (ln >> 4) * 8;
    const float* sp = emb + (size_t)code * D + k0;
    f4_t v0 = *(const f4_t*)sp, v1 = *(const f4_t*)(sp + 4);
    h8_t h;
    h[0] = (_Float16)v0[0]; h[1] = (_Float16)v0[1];
    h[2] = (_Float16)v0[2]; h[3] = (_Float16)v0[3];
    h[4] = (_Float16)v1[0]; h[5] = (_Float16)v1[1];
    h[6] = (_Float16)v1[2]; h[7] = (_Float16)v1[3];
    *(h8_t*)(femb + (size_t)g * 8) = h;
  }
  const int lane = threadIdx.x & 63;
  const int w    = threadIdx.x >> 6;
  const int jdx  = lane & 15, hf = jdx >> 3, jj = jdx & 7;
  #pragma unroll
  for (int cc = 0; cc < 2; ++cc) {
    int k = t * 32 + w * 8 + cc * 4 + (lane >> 4);
    const float* base = emb + (size_t)k * D + hf * 128 + jj;
    float v = base[0];
    float r = v * v;
    #pragma unroll
    for (int m = 1; m < 16; ++m) { v = base[8 * m]; r += v * v; }
    r += __shfl_xor(r, 1, 64);
    r += __shfl_xor(r, 2, 64);
    r += __shfl_xor(r, 4, 64);
    r += __shfl_xor(r, 8, 64);
    if (jdx == 0) { senp[k] = r; ekkb[k] = 0.5f * r - BIAS; }
  }
}

// ---------------- score: MFMA + margin filter -> global candidate lists ----------------
__global__ void __launch_bounds__(THREADS, 2)
vq_score(const float* __restrict__ xin, const _Float16* __restrict__ femb,
         const float* __restrict__ ekkb, int* __restrict__ gcnt,
         unsigned short* __restrict__ gcand) {
  __shared__ alignas(16) char Astage[65536];   // 128 rows x 256 k f16, fragment order
  __shared__ int rowmaxI[MB];
  __shared__ int cnt[MB];
  __shared__ unsigned short cand[MB][CAP];     // 8 KB;  total ~75 KB -> 1 block/CU

  const int tid  = threadIdx.x;
  const int lane = tid & 63;
  const int wid  = tid >> 6;     // 0..7
  const int l15  = lane & 15;
  const int quad = lane >> 4;
  const int rw   = wid >> 2;     // 0..1 : 64-row half
  const int cq   = wid & 3;      // 0..3 : code quarter
  const int r0   = blockIdx.x * MB;

  for (int i = tid; i < MB; i += THREADS) { rowmaxI[i] = 0; cnt[i] = 0; }

  // stage A (clip + f16, chunk-major fragment order: 128 rows x 256 k = 4096 units)
  #pragma unroll
  for (int j = 0; j < 8; ++j) {
    int c = j * THREADS + tid;          // 0..4095
    int ms = c >> 9, kc = (c >> 6) & 7, ln = c & 63;
    int row = ms * 16 + (ln & 15);
    int k0 = kc * 32 + (ln >> 4) * 8;
    const float* ap = xin + (size_t)(r0 + row) * D + k0;
    f4_t v0 = *(const f4_t*)ap, v1 = *(const f4_t*)(ap + 4);
    h8_t h;
    h[0] = (_Float16)clipf(v0[0]); h[1] = (_Float16)clipf(v0[1]);
    h[2] = (_Float16)clipf(v0[2]); h[3] = (_Float16)clipf(v0[3]);
    h[4] = (_Float16)clipf(v1[0]); h[5] = (_Float16)clipf(v1[1]);
    h[6] = (_Float16)clipf(v1[2]); h[7] = (_Float16)clipf(v1[3]);
    *(h8_t*)(Astage + (size_t)c * 16) = h;
  }
  __syncthreads();

  // A fragments -> registers: 64 rows per wave (rw half), 128 VGPR
  h8_t afrag[4][8];
  #pragma unroll
  for (int m = 0; m < 4; ++m)
    #pragma unroll
    for (int kc = 0; kc < 8; ++kc)
      afrag[m][kc] = *(const h8_t*)(Astage +
          (size_t)(((rw * 4 + m) * 512 + kc * 64 + lane) * 16));

  float Gm[4];
  #pragma unroll
  for (int a = 0; a < 4; ++a) Gm[a] = -1e30f;

  // ---- K-loop: explicit register double-buffer; every wait is vmcnt(9), never 0.
  // slot s -> chunk ch = s*4+cq; load order per iter: bnext[0..7] then eknext.
  h8_t bcur[8]; float ekcur;
  {
    const _Float16* bb = femb + (size_t)cq * 4096 + lane * 8;
    #pragma unroll
    for (int kc = 0; kc < 8; ++kc) bcur[kc] = *(const h8_t*)(bb + kc * 512);
    ekcur = ekkb[cq * 16 + l15];
  }

  for (int s = 0; s < SLOTS; ++s) {
    const int sn = (s + 1 < SLOTS) ? s + 1 : s;   // clamped prefetch (always in-bounds)
    h8_t bnext[8]; float eknext;
    {
      const _Float16* bb = femb + (size_t)(sn * 4 + cq) * 4096 + lane * 8;
      #pragma unroll
      for (int kc = 0; kc < 8; ++kc) bnext[kc] = *(const h8_t*)(bb + kc * 512);
      eknext = ekkb[(sn * 4 + cq) * 16 + l15];
    }

    f4_t acc[4];
    #pragma unroll
    for (int m = 0; m < 4; ++m) { f4_t z = {0.f, 0.f, 0.f, 0.f}; acc[m] = z; }
    #pragma unroll
    for (int kc = 0; kc < 8; ++kc)
      #pragma unroll
      for (int m = 0; m < 4; ++m)
        acc[m] = __builtin_amdgcn_mfma_f32_16x16x32_f16(afrag[m][kc], bcur[kc], acc[m], 0, 0, 0);

    const int ch = s * 4 + cq;
    #pragma unroll
    for (int m = 0; m < 4; ++m) {
      float ts[4];
      #pragma unroll
      for (int r = 0; r < 4; ++r) ts[r] = acc[m][r] - ekcur;
      float tmx = fmaxf(fmaxf(ts[0], ts[1]), fmaxf(ts[2], ts[3]));
      if (__any(tmx > Gm[m])) {
        float cmin = 1e30f;
        #pragma unroll
        for (int r = 0; r < 4; ++r) {
          int row_ = rw * 64 + m * 16 + quad * 4 + r;
          float mm = maxrow16(ts[r]);
          if (l15 == 0) atomicMax(&rowmaxI[row_], __float_as_int(mm));
          float cut = __int_as_float(rowmaxI[row_]) - MARGIN;
          cmin = fminf(cmin, cut);
          if (ts[r] >= cut) {
            int sidx = atomicAdd(&cnt[row_], 1);
            if (sidx < CAP) cand[row_][sidx] = (unsigned short)(ch * 16 + l15);
          }
        }
        Gm[m] = cmin;
      }
    }

    #pragma unroll
    for (int kc = 0; kc < 8; ++kc) bcur[kc] = bnext[kc];
    ekcur = eknext;
    if ((s & 31) == 31) __syncthreads();   // keep waves in the same 1MB L2 window
  }
  __syncthreads();

  // dump candidates to global
  for (int i = tid; i < MB; i += THREADS) {
    int c = cnt[i];
    gcnt[r0 + i] = c > CAP ? CAP : c;
  }
  const unsigned int* cu = (const unsigned int*)cand;
  unsigned int* gu = (unsigned int*)gcand + (size_t)r0 * (CAP / 2);
  for (int i = tid; i < MB * (CAP / 2); i += THREADS) gu[i] = cu[i];
}

// ---------------- exact rescore: 8 lanes per candidate, butterfly argmin ----------------
__global__ void __launch_bounds__(256)
vq_rescore(const float* __restrict__ xin, const float* __restrict__ emb,
           const float* __restrict__ senp, const int* __restrict__ gcnt,
           const unsigned short* __restrict__ gcand, float* __restrict__ out,
           float* __restrict__ lossacc) {
  __shared__ float xrow[4][D];
  __shared__ float rpart[4][16];
  __shared__ float blksum;
  const int tid  = threadIdx.x;
  const int lane = tid & 63;
  const int wid  = tid >> 6;
  const int g    = lane >> 3;    // candidate slot within batch (0..7)
  const int e    = lane & 7;     // 32-elem octant (0..7)
  const int r0   = blockIdx.x * 64;
  if (tid == 0) blksum = 0.0f;
  __syncthreads();

  const int lane4 = lane * 4;
  for (int rr = 0; rr < 16; ++rr) {
    const int row = wid + rr * 4;
    f4_t xv = *(const f4_t*)(xin + (size_t)(r0 + row) * D + lane4);
    xv[0] = clipf(xv[0]); xv[1] = clipf(xv[1]); xv[2] = clipf(xv[2]); xv[3] = clipf(xv[3]);
    *(f4_t*)&xrow[wid][lane4] = xv;
    __builtin_amdgcn_wave_barrier();
    if (lane < 16) {   // numpy pairwise sum of x^2 (exact order)
      const int hf = lane >> 3, jj = lane & 7;
      const float* base = &xrow[wid][hf * 128 + jj];
      float v = base[0];
      float rs = v * v;
      #pragma unroll
      for (int m = 1; m < 16; ++m) { v = base[8 * m]; rs += v * v; }
      rpart[wid][lane] = rs;
    }
    __builtin_amdgcn_wave_barrier();
    float p[16];
    #pragma unroll
    for (int j = 0; j < 16; ++j) p[j] = rpart[wid][j];
    float h0 = ((p[0] + p[1]) + (p[2] + p[3])) + ((p[4] + p[5]) + (p[6] + p[7]));
    float h1 = ((p[8] + p[9]) + (p[10] + p[11])) + ((p[12] + p[13]) + (p[14] + p[15]));
    float sx = h0 + h1;

    // hoist this lane's x octant (32 floats)
    f4_t xo[8];
    #pragma unroll
    for (int u = 0; u < 8; ++u) xo[u] = *(const f4_t*)&xrow[wid][e * 32 + u * 4];

    const int nc = gcnt[r0 + row];
    const unsigned short* cl = gcand + (size_t)(r0 + row) * CAP;
    float bd = INFINITY; int bk = 0x7fffffff;
    for (int bi = 0; bi < (nc + 7) >> 3; ++bi) {
      int ci = bi * 8 + g;
      bool valid = ci < nc;
      int k = valid ? cl[ci] : 0;
      const float* ep = emb + (size_t)k * D + e * 32;
      double dd = 0.0;
      #pragma unroll
      for (int u = 0; u < 8; ++u) {
        f4_t ev = *(const f4_t*)(ep + u * 4);
        dd += (double)xo[u][0] * (double)ev[0] + (double)xo[u][1] * (double)ev[1]
            + (double)xo[u][2] * (double)ev[2] + (double)xo[u][3] * (double)ev[3];
      }
      dd += __shfl_xor(dd, 1, 64);
      dd += __shfl_xor(dd, 2, 64);
      dd += __shfl_xor(dd, 4, 64);   // all 8 lanes of the group hold the full dot
      float T1 = sx + senp[k];       // fp32, numpy op order
      float T2 = (float)(2.0 * dd);
      float d  = valid ? (T1 - T2) : INFINITY;
      int   kk = valid ? k : 0x7fffffff;
      if (d < bd || (d == bd && kk < bk)) { bd = d; bk = kk; }
    }
    // cross-group lexicographic argmin (associative & commutative -> exact)
    #pragma unroll
    for (int off = 8; off < 64; off <<= 1) {
      float od = __shfl_xor(bd, off, 64);
      int   ok = __shfl_xor(bk, off, 64);
      if (od < bd || (od == bd && ok < bk)) { bd = od; bk = ok; }
    }

    f4_t ev = *(const f4_t*)(emb + (size_t)bk * D + lane4);
    *(f4_t*)(out + (size_t)(r0 + row) * D + lane4) = ev;
    float ls = 0.0f;
    #pragma unroll
    for (int i = 0; i < 4; ++i) { float df = ev[i] - xv[i]; ls += df * df; }
    #pragma unroll
    for (int off = 1; off < 64; off <<= 1) ls += __shfl_xor(ls, off, 64);
    if (lane == 0) atomicAdd(&blksum, ls);
  }
  __syncthreads();
  if (tid == 0) atomicAdd(lossacc, blksum);
}

// ---------------- finalize loss ----------------
__global__ void vq_fin(const float* __restrict__ lossacc, float* __restrict__ out) {
  out[NOUT] = 1.25f * lossacc[0] / 8388608.0f;
}

extern "C" void kernel_launch(void* const* d_in, const int* in_sizes, int n_in,
                              void* d_out, int out_size, void* d_ws, size_t ws_size,
                              hipStream_t stream) {
  const float* xin = (const float*)d_in[0];
  const float* emb = (const float*)d_in[1];
  float* out = (float*)d_out;
  _Float16* femb = (_Float16*)d_ws;                 // 4 MB (512 chunks x 8 KB)
  float* F       = (float*)d_ws + 1048576;
  float* senp    = F;                               // 8192
  float* ekkb    = F + 8192;                        // 8192
  float* lossacc = F + 16384;                       // 1
  int*   gcnt    = (int*)(F + 16640);               // 32768 ints
  unsigned short* gcand = (unsigned short*)(F + 16640 + 32768);  // 32768*32 u16
  vq_packsetup<<<dim3(256), dim3(256), 0, stream>>>(emb, femb, senp, ekkb, lossacc);
  vq_score<<<dim3(NROWS / MB), dim3(THREADS), 0, stream>>>(xin, femb, ekkb, gcnt, gcand);
  vq_rescore<<<dim3(NROWS / 64), dim3(256), 0, stream>>>(xin, emb, senp, gcnt, gcand, out, lossacc);
  vq_fin<<<dim3(1), dim3(1), 0, stream>>>(lossacc, out);
}